// Round 2
// baseline (400.479 us; speedup 1.0000x reference)
//
#include <hip/hip_runtime.h>

// L1 loss between CIE-Lab L channels of two (64,3,512,512) f32 images.
//
// R4 theory: R3 falsified the MLP theory (forced 12-deep asm loads, identical
// 130us; L3-resident replay identical; delivered BW only 5 B/cyc/CU). The
// only model fitting all counters: the transcendental pipe (v_exp/v_log) is
// saturated -- 16 trans/pixel-pair at ~1-2 lanes/cyc/SIMD ~= 110-130us, with
// main VALU 26% busy and memory idle. Fix: ZERO transcendentals.
//   a^2.4 = (a^2)^(6/5): bit-hack seed u ~ X^(-1/5) (K5 - bits/5, umulhi
//     magic), 4 FMA-only Newton iters (self-correcting), hi = (X*u^2)^2.
//   cbrt(Y): seed z ~ Y^(-1/3) (K3 - bits/3), 3 Newton iters, cb = Y*z^2.
// All replacement work runs at full VALU rate with 6 independent chains per
// pixel for ILP. Predicted: 130 -> 60-75us, VALUBusy -> >75%.

#define HW4   65536      // float4 groups per channel plane (512*512/4)
#define CHW4  196608     // 3*HW4 float4 groups per image
#define HALFG 2097152    // half of total groups = thread count
#define NPIX  16777216

// inverse sRGB companding on raw x in [-1,1], s=(x+1)/2 folded into FMAs:
//   a  = (s+0.055)/1.055 = fma(x, 0.47393364, 0.52606636)
//   lo = s/12.92         = fma(x, 0.03869969, 0.03869969)
//   hi = a^2.4 = (a^2)^(6/5) via Newton fifth-root, NO transcendentals.
__device__ __forceinline__ float srgb_expand(float x) {
    float a = fmaf(x, 0.47393364f, 0.52606636f);   // in [0.0266, 1.0]
    float X = a * a;                                // in [7.1e-4, 1.0], normal
    unsigned B = __float_as_uint(X);
    // seed u ~ X^(-1/5): (6/5)*bits(1.0) - bits/5 ; exact /5 via magic mulhi
    unsigned ub = 1278423859u - (__umulhi(B, 0xCCCCCCCDu) >> 2);
    float u = __uint_as_float(ub);
    // Newton for u = X^(-1/5): u <- u * (1.2 - 0.2*X*u^5); fixed point exact.
    float X5 = X * 0.2f;
    #pragma unroll
    for (int i = 0; i < 4; ++i) {
        float u2 = u * u;
        float u4 = u2 * u2;
        float u5 = u4 * u;
        float t  = fmaf(-X5, u5, 1.2f);
        u = u * t;
    }
    float r  = X * (u * u);       // X*u^2 ; r^2 = X^2*u^4 = X^(6/5) = a^2.4
    float hi = r * r;
    float lo = fmaf(x, 0.03869969f, 0.03869969f);
    return (x > -0.9191f) ? hi : lo;   // s>0.04045 <=> x>-0.9191
}

// Lab f(Y); the 116*f-16 affine is folded into caller (|dL| = 116*|df|)
__device__ __forceinline__ float lab_f(float r, float g, float b) {
    float lr = srgb_expand(r);
    float lg = srgb_expand(g);
    float lb = srgb_expand(b);
    float Y  = fmaf(0.2126729f, lr, fmaf(0.7151522f, lg, 0.0721750f * lb));
    // cbrt(Y) via Newton on z ~ Y^(-1/3); Y in (0.008856, 1.0] on taken path.
    unsigned B = __float_as_uint(Y);
    unsigned zb = 1420470954u - (__umulhi(B, 0xAAAAAAABu) >> 1);
    float z = __uint_as_float(zb);
    float Y3 = Y * 0.33333334f;
    #pragma unroll
    for (int i = 0; i < 3; ++i) {
        float z2 = z * z;
        float z3 = z2 * z;
        float t  = fmaf(-Y3, z3, 1.3333334f);
        z = z * t;
    }
    // Y->0: z overflows/NaNs in dead operand; select takes linear branch.
    float cb  = Y * (z * z);
    float lin = fmaf(7.787f, Y, 0.13793103f);      // kappa*Y + 16/116
    return (Y > 0.008856f) ? cb : lin;
}

__device__ __forceinline__ float group_absdiff(
        float4 gr, float4 gg, float4 gb,
        float4 tr, float4 tg, float4 tb) {
    float s;
    s  = fabsf(lab_f(gr.x, gg.x, gb.x) - lab_f(tr.x, tg.x, tb.x));
    s += fabsf(lab_f(gr.y, gg.y, gb.y) - lab_f(tr.y, tg.y, tb.y));
    s += fabsf(lab_f(gr.z, gg.z, gb.z) - lab_f(tr.z, tg.z, tb.z));
    s += fabsf(lab_f(gr.w, gg.w, gb.w) - lab_f(tr.w, tg.w, tb.w));
    return s;
}

// Inline-asm 16B load: distinct live dest per load (12-deep MLP), proven
// correct in R3; keep so group B's loads prefetch under group A's compute.
__device__ __forceinline__ float4 gload(const float4* p) {
    float4 r;
    asm volatile("global_load_dwordx4 %0, %1, off" : "=v"(r) : "v"(p));
    return r;
}

__global__ void zero_out_kernel(float* out) {
    if (threadIdx.x == 0) out[0] = 0.0f;
}

__global__ __launch_bounds__(512) void lum_loss_kernel(
        const float* __restrict__ gen,
        const float* __restrict__ tgt,
        float* __restrict__ out) {
    const float4* gp = (const float4*)gen;
    const float4* tp = (const float4*)tgt;

    int t  = blockIdx.x * 512 + threadIdx.x;   // 0 .. HALFG-1
    int ga = t;                                 // group A: first half
    int gb = t + HALFG;                         // group B: second half
    int basea = (ga >> 16) * CHW4 + (ga & 65535);
    int baseb = (gb >> 16) * CHW4 + (gb & 65535);

    float4 agr = gload(gp + basea);
    float4 agg = gload(gp + basea + HW4);
    float4 agb = gload(gp + basea + 2 * HW4);
    float4 atr = gload(tp + basea);
    float4 atg = gload(tp + basea + HW4);
    float4 atb = gload(tp + basea + 2 * HW4);
    float4 bgr = gload(gp + baseb);
    float4 bgg = gload(gp + baseb + HW4);
    float4 bgb = gload(gp + baseb + 2 * HW4);
    float4 btr = gload(tp + baseb);
    float4 btg = gload(tp + baseb + HW4);
    float4 btb = gload(tp + baseb + 2 * HW4);

    // wait for group A only; B's 6 loads stay in flight under A's compute
    asm volatile("s_waitcnt vmcnt(6)" ::: "memory");
    __builtin_amdgcn_sched_barrier(0);   // rule #18: pin compute after waitcnt
    float a = group_absdiff(agr, agg, agb, atr, atg, atb);

    asm volatile("s_waitcnt vmcnt(0)" ::: "memory");
    __builtin_amdgcn_sched_barrier(0);
    a += group_absdiff(bgr, bgg, bgb, btr, btg, btb);
    a *= 116.0f;

    // wave64 reduce
    #pragma unroll
    for (int off = 32; off > 0; off >>= 1)
        a += __shfl_down(a, off, 64);

    __shared__ float smem[8];
    int lane = threadIdx.x & 63;
    int wave = threadIdx.x >> 6;
    if (lane == 0) smem[wave] = a;
    __syncthreads();

    if (threadIdx.x == 0) {
        float s = ((smem[0] + smem[1]) + (smem[2] + smem[3]))
                + ((smem[4] + smem[5]) + (smem[6] + smem[7]));
        atomicAdd(out, s * (1.0f / (float)NPIX));
    }
}

extern "C" void kernel_launch(void* const* d_in, const int* in_sizes, int n_in,
                              void* d_out, int out_size, void* d_ws, size_t ws_size,
                              hipStream_t stream) {
    const float* gen = (const float*)d_in[0];
    const float* tgt = (const float*)d_in[1];
    float* out = (float*)d_out;

    zero_out_kernel<<<1, 64, 0, stream>>>(out);
    // 2,097,152 threads, 2 float4-groups (8 pixels) each = 16,777,216 pixels
    lum_loss_kernel<<<4096, 512, 0, stream>>>(gen, tgt, out);
}

// Round 3
// 388.947 us; speedup vs baseline: 1.0297x; 1.0297x over previous
//
#include <hip/hip_runtime.h>

// L1 loss between CIE-Lab L channels of two (64,3,512,512) f32 images.
//
// R5: REVERT to the R0 kernel — it is at the roofline.
// Evidence across R0-R4: delivered READ bandwidth pins at 3.10-3.15 TB/s for
// every variant (compiler-scheduled loads, forced 12-deep asm MLP, trans math,
// Newton-only math, HBM-fed, and fully-L3-resident replays all ~128-130us).
// m13's "6.29 TB/s float4 copy" must be TOTAL bus traffic (else a copy would
// imply 12.6 TB/s > 8 TB/s spec) => ~3.15 TB/s per direction. A read-only
// kernel caps at the per-direction read-path ceiling ~3.15 TB/s; L3-resident
// replays are identical because Infinity Cache sits behind the same path.
// Floor = 402.65 MB / 3.15 TB/s = 127.8 us; R0 measured 127.96 us (+0.2%).
// R3 (MLP fix): null. R4 (zero-trans Newton): -15% regression (extra VALU).
// No on-CU change can move a memory-delivery floor. This is the roofline.

#define HW4   65536      // HW/4 float4 units per channel plane
#define CHW4  196608     // 3*HW/4 float4 units per image
#define NPIX  16777216

__device__ __forceinline__ float fast_log2(float x) {
#if __has_builtin(__builtin_amdgcn_logf)
    return __builtin_amdgcn_logf(x);      // v_log_f32 (log2)
#else
    return __log2f(x);
#endif
}
__device__ __forceinline__ float fast_exp2(float x) {
#if __has_builtin(__builtin_amdgcn_exp2f)
    return __builtin_amdgcn_exp2f(x);     // v_exp_f32 (2^x)
#else
    return exp2f(x);
#endif
}

// inverse sRGB companding on raw x in [-1,1], s=(x+1)/2 folded into FMAs:
//   a  = (s+0.055)/1.055 = fma(x, 0.47393364, 0.52606636)
//   lo = s/12.92         = fma(x, 0.03869969, 0.03869969)
//   hi = a^2.4 = exp2(2.4*log2(a));  select on s>0.04045 <=> x>-0.9191
__device__ __forceinline__ float srgb_expand(float x) {
    float a  = fmaf(x, 0.47393364f, 0.52606636f);
    float hi = fast_exp2(2.4f * fast_log2(a));
    float lo = fmaf(x, 0.03869969f, 0.03869969f);
    return (x > -0.9191f) ? hi : lo;
}

// Lab f(Y); the 116*f-16 affine is folded into caller (|dL| = 116*|df|)
__device__ __forceinline__ float lab_f(float r, float g, float b) {
    float lr = srgb_expand(r);
    float lg = srgb_expand(g);
    float lb = srgb_expand(b);
    float Y  = fmaf(0.2126729f, lr, fmaf(0.7151522f, lg, 0.0721750f * lb));
    float cb = fast_exp2(0.333333333333f * fast_log2(Y));
    float lin = fmaf(7.787f, Y, 16.0f / 116.0f);
    return (Y > 0.008856f) ? cb : lin;
}

__device__ __forceinline__ float group_absdiff(
        float4 gr, float4 gg, float4 gb,
        float4 tr, float4 tg, float4 tb) {
    float s;
    s  = fabsf(lab_f(gr.x, gg.x, gb.x) - lab_f(tr.x, tg.x, tb.x));
    s += fabsf(lab_f(gr.y, gg.y, gb.y) - lab_f(tr.y, tg.y, tb.y));
    s += fabsf(lab_f(gr.z, gg.z, gb.z) - lab_f(tr.z, tg.z, tb.z));
    s += fabsf(lab_f(gr.w, gg.w, gb.w) - lab_f(tr.w, tg.w, tb.w));
    return s;
}

__global__ void zero_out_kernel(float* out) {
    if (threadIdx.x == 0) out[0] = 0.0f;
}

__global__ __launch_bounds__(512, 4) void lum_loss_kernel(
        const float* __restrict__ gen,
        const float* __restrict__ tgt,
        float* __restrict__ out) {
    const float4* gp = (const float4*)gen;
    const float4* tp = (const float4*)tgt;

    // thread t handles adjacent float4-groups 2t and 2t+1 (same batch image:
    // group index within plane is even, +1 never crosses HW4 boundary).
    int t    = blockIdx.x * 512 + threadIdx.x;     // 0 .. 2M-1
    int g0   = t << 1;
    int b    = g0 >> 16;                           // g0 / HW4
    int i    = g0 & 65535;                         // g0 % HW4
    int base = b * CHW4 + i;

    float4 gr0 = gp[base];
    float4 gr1 = gp[base + 1];
    float4 gg0 = gp[base + HW4];
    float4 gg1 = gp[base + HW4 + 1];
    float4 gb0 = gp[base + 2 * HW4];
    float4 gb1 = gp[base + 2 * HW4 + 1];
    float4 tr0 = tp[base];
    float4 tr1 = tp[base + 1];
    float4 tg0 = tp[base + HW4];
    float4 tg1 = tp[base + HW4 + 1];
    float4 tb0 = tp[base + 2 * HW4];
    float4 tb1 = tp[base + 2 * HW4 + 1];

    float a = group_absdiff(gr0, gg0, gb0, tr0, tg0, tb0)
            + group_absdiff(gr1, gg1, gb1, tr1, tg1, tb1);
    a *= 116.0f;

    // wave64 reduce
    #pragma unroll
    for (int off = 32; off > 0; off >>= 1)
        a += __shfl_down(a, off, 64);

    __shared__ float smem[8];
    int lane = threadIdx.x & 63;
    int wave = threadIdx.x >> 6;
    if (lane == 0) smem[wave] = a;
    __syncthreads();

    if (threadIdx.x == 0) {
        float s = ((smem[0] + smem[1]) + (smem[2] + smem[3]))
                + ((smem[4] + smem[5]) + (smem[6] + smem[7]));
        atomicAdd(out, s * (1.0f / (float)NPIX));
    }
}

extern "C" void kernel_launch(void* const* d_in, const int* in_sizes, int n_in,
                              void* d_out, int out_size, void* d_ws, size_t ws_size,
                              hipStream_t stream) {
    const float* gen = (const float*)d_in[0];
    const float* tgt = (const float*)d_in[1];
    float* out = (float*)d_out;

    zero_out_kernel<<<1, 64, 0, stream>>>(out);
    // 2,097,152 threads, 2 float4-groups (8 pixels) each = 16,777,216 pixels
    lum_loss_kernel<<<4096, 512, 0, stream>>>(gen, tgt, out);
}